// Round 5
// baseline (162.573 us; speedup 1.0000x reference)
//
#include <hip/hip_runtime.h>

#define N_NODES 50000
#define N_EDGES 800000
#define CH 128
#define SLOT 64                      // padded CSR row capacity (max degree ~40, Poisson mu=16)
#define NB 196                       // buckets of 256 rows
#define FBLK 196                     // fill blocks
#define EPB 4096                     // edges per fill block (16/thread)
#define SCAP 64                      // per-(block,bucket) slice cap (Poisson 21, P(>64)~1e-13)
#define SUB 4                        // build sub-blocks per bucket (64 rows each)
#define RPB 64                       // rows per build block
#define GRID (FBLK + 782)            // 978: gidx%5==0 -> fill (196), else gemm (782)

typedef __attribute__((ext_vector_type(8))) short bf16x8;
typedef __attribute__((ext_vector_type(4))) float f32x4;

static __device__ inline unsigned f2bf(float f) {
    union { float f; unsigned u; } v; v.f = f;
    unsigned r = v.u + 0x7fff + ((v.u >> 16) & 1);   // RNE
    return r >> 16;
}
static __device__ inline float bflo(unsigned v) { union { unsigned u; float f; } c; c.u = v << 16; return c.f; }
static __device__ inline float bfhi(unsigned v) { union { unsigned u; float f; } c; c.u = v & 0xffff0000u; return c.f; }

// ---- prep: W (f32 [k][n]) -> wT (bf16 [n][k]); no cursors needed anymore ----
__global__ __launch_bounds__(256) void k_prep(const float* __restrict__ W,
                                              unsigned short* __restrict__ wT) {
    int t = blockIdx.x * 256 + threadIdx.x;
    if (t < CH * CH) {
        int n = t >> 7, k = t & 127;
        wT[t] = (unsigned short)f2bf(W[k * CH + n]);
    }
}

// ---- FUSED: LDS-staged radix partition (pass A) || y = bf16(x @ W) ----
// Round-4 lesson: atomics were never the wall; 800K random 4B scatter stores were
// (~64 distinct lines per wave-store, partial-line L2 allocate+merge ~ 40us).
// New pass A: bin 4096 edges/block into per-bucket LDS slices, then ONE coalesced
// wave-store per (block,bucket) into a PRIVATE global slice. Zero global atomics,
// every global write is a contiguous burst. Counts go out block-major (coalesced).
__global__ __launch_bounds__(256) void k_fgA(const int* __restrict__ rowv,
                                             const int* __restrict__ colv,
                                             const float* __restrict__ x,
                                             const unsigned short* __restrict__ wT,
                                             unsigned* __restrict__ pedges,
                                             int* __restrict__ cnts,
                                             unsigned short* __restrict__ yh) {
    __shared__ unsigned stage[NB * SCAP];   // 50.2 KB: per-bucket slice, rotation-swizzled
    __shared__ int scnt[NB];
    int gidx = blockIdx.x;
    int t = threadIdx.x;

    if (gidx % 5 == 0) {
        // ---- fill: 4096 edges, 16/thread, all loads issued up-front for ILP ----
        int fbid = gidx / 5;
        int e0 = fbid * EPB + t;
        int r_[16], c_[16];
        #pragma unroll
        for (int j = 0; j < 16; ++j) {
            int e = e0 + j * 256;
            bool v = e < N_EDGES;
            r_[j] = v ? rowv[e] : -1;
            c_[j] = v ? colv[e] : 0;
        }
        if (t < NB) scnt[t] = 0;
        __syncthreads();
        #pragma unroll
        for (int j = 0; j < 16; ++j) {
            if (r_[j] >= 0) {
                int b = r_[j] >> 8;
                int p = atomicAdd(&scnt[b], 1);            // LDS atomic
                if (p < SCAP)                               // slot rotated by b: bank = (p+b)&31
                    stage[b * SCAP + ((p + b) & (SCAP - 1))] =
                        ((unsigned)(r_[j] & 255) << 16) | (unsigned)c_[j];
            }
        }
        __syncthreads();
        // ---- flush: wave w handles 49 buckets; one coalesced store per bucket ----
        int w = t >> 6, ln = t & 63;
        for (int b = w * 49; b < w * 49 + 49; ++b) {
            int cnt = scnt[b]; if (cnt > SCAP) cnt = SCAP;
            if (ln < cnt)
                pedges[((size_t)b * FBLK + fbid) * SCAP + ln] =
                    stage[b * SCAP + (((ln) + b) & (SCAP - 1))];
        }
        if (t < NB) {
            int cnt = scnt[t]; if (cnt > SCAP) cnt = SCAP;
            cnts[(size_t)fbid * NB + t] = cnt;             // block-major, coalesced
        }
        return;
    }

    // ---- gemm: 64 rows/block, 4 waves, wave w -> rows 16w..16w+15 ----
    int row0 = (gidx - (gidx + 4) / 5) * 64;
    int lane = t & 63, w = t >> 6;
    int m = lane & 15, q = lane >> 4;

    int row = row0 + 16 * w + m;
    int rc = row < N_NODES ? row : N_NODES - 1;
    const float4* xr = (const float4*)(x + (size_t)rc * CH);
    bf16x8 afr[4];
    #pragma unroll
    for (int kk = 0; kk < 4; ++kk) {
        float4 a0 = xr[kk * 8 + q * 2];
        float4 a1 = xr[kk * 8 + q * 2 + 1];
        bf16x8 a;
        a[0] = (short)f2bf(a0.x); a[1] = (short)f2bf(a0.y);
        a[2] = (short)f2bf(a0.z); a[3] = (short)f2bf(a0.w);
        a[4] = (short)f2bf(a1.x); a[5] = (short)f2bf(a1.y);
        a[6] = (short)f2bf(a1.z); a[7] = (short)f2bf(a1.w);
        afr[kk] = a;
    }

    f32x4 acc[8];
    #pragma unroll
    for (int c = 0; c < 8; ++c) acc[c] = (f32x4){0.f, 0.f, 0.f, 0.f};

    #pragma unroll
    for (int c = 0; c < 8; ++c) {
        int n = c * 16 + m;
        const bf16x8* wrow = (const bf16x8*)(wT + (size_t)n * CH);
        #pragma unroll
        for (int kk = 0; kk < 4; ++kk)
            acc[c] = __builtin_amdgcn_mfma_f32_16x16x32_bf16(afr[kk], wrow[kk * 4 + q], acc[c], 0, 0, 0);
    }

    #pragma unroll
    for (int c = 0; c < 8; ++c) {
        #pragma unroll
        for (int r = 0; r < 4; ++r) {
            int orow = row0 + 16 * w + q * 4 + r;
            if (orow < N_NODES)
                yh[(size_t)orow * CH + c * 16 + m] = (unsigned short)f2bf(acc[c][r]);
        }
    }
}

// ---- build: (bucket, 64-row slice) per block; scan the bucket's 196 private
// slices with a 2-deep software pipeline (load fb+1 while binning fb), bin into
// LDS, write csrP coalesced. Emits deg/dinv. Zero global atomics.
__global__ __launch_bounds__(256) void k_build(const int* __restrict__ cnts,
                                               const unsigned* __restrict__ pedges,
                                               unsigned short* __restrict__ csrP,
                                               int* __restrict__ deg,
                                               float* __restrict__ dinv) {
    __shared__ unsigned short bins[RPB][SLOT];   // 8KB
    __shared__ int rcnt[RPB];
    int b = blockIdx.x >> 2;         // bucket
    int s = blockIdx.x & 3;          // 64-row slice within bucket
    int t = threadIdx.x;
    int w = t >> 6, ln = t & 63;
    if (t < RPB) rcnt[t] = 0;
    __syncthreads();

    // wave w scans fb = w, w+4, ..., pipelined
    const unsigned NOEDGE = 0xffffffffu;         // rlo=0xffff -> never matches slice
    int fb = w;
    int cnt0 = cnts[(size_t)fb * NB + b];
    unsigned u0 = (ln < cnt0) ? pedges[((size_t)b * FBLK + fb) * SCAP + ln] : NOEDGE;
    for (; fb + 4 < FBLK; ) {
        int fb1 = fb + 4;
        int cnt1 = cnts[(size_t)fb1 * NB + b];
        unsigned u1 = (ln < cnt1) ? pedges[((size_t)b * FBLK + fb1) * SCAP + ln] : NOEDGE;
        if (u0 != NOEDGE) {
            int rlo = u0 >> 16;
            if ((rlo >> 6) == s) {
                int p = atomicAdd(&rcnt[rlo & 63], 1);
                if (p < SLOT) bins[rlo & 63][p] = (unsigned short)(u0 & 0xffff);
            }
        }
        u0 = u1; fb = fb1;
    }
    if (u0 != NOEDGE) {
        int rlo = u0 >> 16;
        if ((rlo >> 6) == s) {
            int p = atomicAdd(&rcnt[rlo & 63], 1);
            if (p < SLOT) bins[rlo & 63][p] = (unsigned short)(u0 & 0xffff);
        }
    }
    __syncthreads();

    int row0 = b * 256 + s * RPB;
    if (t < RPB) {
        int row = row0 + t;
        if (row < N_NODES) {
            int d = rcnt[t];
            deg[row] = d;
            dinv[row] = rsqrtf((float)(d > 0 ? d : 1));
        }
    }
    int rmax = N_NODES - row0;
    if (rmax <= 0) return;
    if (rmax > RPB) rmax = RPB;
    uint4* dst = (uint4*)(csrP + (size_t)row0 * SLOT);
    const uint4* src = (const uint4*)bins;
    for (int k = t; k < rmax * 8; k += 256)      // 8 uint4 per row (128B)
        dst[k] = src[k];
}

// ---- per-node gather-reduce: 16 y-row gathers in flight, dense dinv ----
__global__ __launch_bounds__(256) void k_agg(const int* __restrict__ deg,
                                             const float* __restrict__ dinv,
                                             const unsigned short* __restrict__ csrP,
                                             const unsigned short* __restrict__ yh,
                                             float* __restrict__ out) {
    int gid = blockIdx.x * 256 + threadIdx.x;
    int n = gid >> 6;
    int lane = threadIdx.x & 63;
    if (n >= N_NODES) return;
    int d = deg[n];
    int cnt = d < SLOT ? d : SLOT;
    float dr = dinv[n];
    const unsigned* __restrict__ y2 = (const unsigned*)yh;    // 2 bf16 per uint
    const uint4* __restrict__ crow = (const uint4*)(csrP + (size_t)n * SLOT);
    float ax = 0.f, ay = 0.f;
    int j = 0;
    for (; j + 16 <= cnt; j += 16) {          // 16 independent gathers in flight
        uint4 ca = crow[j >> 3];
        uint4 cb = crow[(j >> 3) + 1];
        int c_[16];
        c_[0] = ca.x & 0xffff;  c_[1] = ca.x >> 16;
        c_[2] = ca.y & 0xffff;  c_[3] = ca.y >> 16;
        c_[4] = ca.z & 0xffff;  c_[5] = ca.z >> 16;
        c_[6] = ca.w & 0xffff;  c_[7] = ca.w >> 16;
        c_[8] = cb.x & 0xffff;  c_[9] = cb.x >> 16;
        c_[10] = cb.y & 0xffff; c_[11] = cb.y >> 16;
        c_[12] = cb.z & 0xffff; c_[13] = cb.z >> 16;
        c_[14] = cb.w & 0xffff; c_[15] = cb.w >> 16;
        unsigned v_[16];
        #pragma unroll
        for (int u = 0; u < 16; ++u) v_[u] = y2[c_[u] * 64 + lane];   // long-latency first
        float w_[16];
        #pragma unroll
        for (int u = 0; u < 16; ++u) w_[u] = dinv[c_[u]];             // L2-hot broadcast
        #pragma unroll
        for (int u = 0; u < 16; ++u) {
            ax = fmaf(bflo(v_[u]), w_[u], ax);
            ay = fmaf(bfhi(v_[u]), w_[u], ay);
        }
    }
    for (; j + 8 <= cnt; j += 8) {            // 8-wide mid loop
        uint4 cc = crow[j >> 3];
        int c0 = cc.x & 0xffff, c1 = cc.x >> 16;
        int c2 = cc.y & 0xffff, c3 = cc.y >> 16;
        int c4 = cc.z & 0xffff, c5 = cc.z >> 16;
        int c6 = cc.w & 0xffff, c7 = cc.w >> 16;
        unsigned v0 = y2[c0 * 64 + lane];
        unsigned v1 = y2[c1 * 64 + lane];
        unsigned v2 = y2[c2 * 64 + lane];
        unsigned v3 = y2[c3 * 64 + lane];
        unsigned v4 = y2[c4 * 64 + lane];
        unsigned v5 = y2[c5 * 64 + lane];
        unsigned v6 = y2[c6 * 64 + lane];
        unsigned v7 = y2[c7 * 64 + lane];
        float w0 = dinv[c0], w1 = dinv[c1], w2 = dinv[c2], w3 = dinv[c3];
        float w4 = dinv[c4], w5 = dinv[c5], w6 = dinv[c6], w7 = dinv[c7];
        ax = fmaf(bflo(v0), w0, ax); ay = fmaf(bfhi(v0), w0, ay);
        ax = fmaf(bflo(v1), w1, ax); ay = fmaf(bfhi(v1), w1, ay);
        ax = fmaf(bflo(v2), w2, ax); ay = fmaf(bfhi(v2), w2, ay);
        ax = fmaf(bflo(v3), w3, ax); ay = fmaf(bfhi(v3), w3, ay);
        ax = fmaf(bflo(v4), w4, ax); ay = fmaf(bfhi(v4), w4, ay);
        ax = fmaf(bflo(v5), w5, ax); ay = fmaf(bfhi(v5), w5, ay);
        ax = fmaf(bflo(v6), w6, ax); ay = fmaf(bfhi(v6), w6, ay);
        ax = fmaf(bflo(v7), w7, ax); ay = fmaf(bfhi(v7), w7, ay);
    }
    for (; j < cnt; ++j) {
        int c = csrP[(size_t)n * SLOT + j];
        float wc = dinv[c];
        unsigned v = y2[c * 64 + lane];
        ax = fmaf(bflo(v), wc, ax); ay = fmaf(bfhi(v), wc, ay);
    }
    ((float2*)out)[n * 64 + lane] = make_float2(ax * dr, ay * dr);
}

extern "C" void kernel_launch(void* const* d_in, const int* in_sizes, int n_in,
                              void* d_out, int out_size, void* d_ws, size_t ws_size,
                              hipStream_t stream) {
    const float* x = (const float*)d_in[0];
    const float* W = (const float*)d_in[1];
    const int* edge = (const int*)d_in[2];
    const int* rowv = edge;            // edge_index[0][:]
    const int* colv = edge + N_EDGES;  // edge_index[1][:]
    float* out = (float*)d_out;

    // ws layout: pedges(u32 private slices) | cnts | csrP(u16) | yh(bf16) | deg | dinv | wT
    char* p = (char*)d_ws;
    unsigned* pedges = (unsigned*)p;               p += (size_t)NB * FBLK * SCAP * 4;   // 9.83 MB
    int* cnts = (int*)p;                           p += (size_t)FBLK * NB * 4;          // 154 KB
    unsigned short* csrP = (unsigned short*)p;     p += (size_t)N_NODES * SLOT * 2;     // 6.4 MB
    unsigned short* yh = (unsigned short*)p;       p += (size_t)N_NODES * CH * 2;       // 12.8 MB
    int* deg = (int*)p;                            p += (size_t)N_NODES * 4;
    float* dinv = (float*)p;                       p += (size_t)N_NODES * 4;
    unsigned short* wT = (unsigned short*)p;       // + CH*CH*2

    k_prep <<<64, 256, 0, stream>>>(W, wT);
    k_fgA  <<<GRID, 256, 0, stream>>>(rowv, colv, x, wT, pedges, cnts, yh);
    k_build<<<NB * SUB, 256, 0, stream>>>(cnts, pedges, csrP, deg, dinv);
    k_agg  <<<(N_NODES * 64 + 255) / 256, 256, 0, stream>>>(deg, dinv, csrP, yh, out);
}

// Round 6
// 143.195 us; speedup vs baseline: 1.1353x; 1.1353x over previous
//
#include <hip/hip_runtime.h>

#define N_NODES 50000
#define N_EDGES 800000
#define CH 128
#define SLOT 64                      // padded CSR row capacity (max degree ~40, Poisson mu=16)
#define NB 196                       // buckets of 256 rows
#define EPB 2048                     // edges per fill block (8/thread)
#define FBLK ((N_EDGES + EPB - 1) / EPB)   // 391 fill blocks
#define SCAP 32                      // per-(block,bucket) slice cap (lambda=10.4, P(>32)~4e-9)
#define GB 782                       // gemm blocks (64 rows each)
#define GRID (FBLK + GB)             // 1173: gidx%3==0 -> fill (391), else gemm (782)

typedef __attribute__((ext_vector_type(8))) short bf16x8;
typedef __attribute__((ext_vector_type(4))) float f32x4;

static __device__ inline unsigned f2bf(float f) {
    union { float f; unsigned u; } v; v.f = f;
    unsigned r = v.u + 0x7fff + ((v.u >> 16) & 1);   // RNE
    return r >> 16;
}
static __device__ inline float bflo(unsigned v) { union { unsigned u; float f; } c; c.u = v << 16; return c.f; }
static __device__ inline float bfhi(unsigned v) { union { unsigned u; float f; } c; c.u = v & 0xffff0000u; return c.f; }

// ---- FUSED: LDS-staged radix partition (pass A) || y = bf16(x @ W) ----
// Round-5 lesson: the 50KB stage capped the WHOLE kernel (gemm blocks included) at
// 3 blocks/CU and killed the TLP that hides fill latency. EPB=2048/SCAP=32 puts
// LDS at 25.9KB -> 6 blocks/CU for both roles, same coalesced-burst write path
// (zero global atomics, every pedges store is a 128B half-wave burst).
// W is converted inline in the gemm role (measured free in rounds 0->1): no k_prep.
__global__ __launch_bounds__(256) void k_fgA(const int* __restrict__ rowv,
                                             const int* __restrict__ colv,
                                             const float* __restrict__ x,
                                             const float* __restrict__ W,
                                             unsigned* __restrict__ pedges,
                                             int* __restrict__ cnts,
                                             unsigned short* __restrict__ yh) {
    __shared__ unsigned stage[NB * SCAP];   // 25.1 KB, rotation-swizzled per bucket
    __shared__ int scnt[NB];
    int gidx = blockIdx.x;
    int t = threadIdx.x;

    if (gidx % 3 == 0) {
        // ---- fill: 2048 edges, 8/thread, loads issued up-front for ILP ----
        int fbid = gidx / 3;
        int e0 = fbid * EPB + t;
        int r_[8], c_[8];
        #pragma unroll
        for (int j = 0; j < 8; ++j) {
            int e = e0 + j * 256;
            bool v = e < N_EDGES;
            r_[j] = v ? rowv[e] : -1;
            c_[j] = v ? colv[e] : 0;
        }
        if (t < NB) scnt[t] = 0;
        __syncthreads();
        #pragma unroll
        for (int j = 0; j < 8; ++j) {
            if (r_[j] >= 0) {
                int b = r_[j] >> 8;
                int p = atomicAdd(&scnt[b], 1);             // LDS atomic
                if (p < SCAP)                               // bank = (p+b)&31: rotated
                    stage[b * SCAP + ((p + b) & (SCAP - 1))] =
                        ((unsigned)(r_[j] & 255) << 16) | (unsigned)c_[j];
            }
        }
        __syncthreads();
        // ---- flush: half-wave hw handles buckets hw, hw+8, ...; 128B bursts ----
        int hw = t >> 5, ln = t & 31;
        for (int b = hw; b < NB; b += 8) {
            int cnt = scnt[b]; if (cnt > SCAP) cnt = SCAP;
            if (ln < cnt)
                pedges[((size_t)b * FBLK + fbid) * SCAP + ln] =
                    stage[b * SCAP + ((ln + b) & (SCAP - 1))];
        }
        if (t < NB) {
            int cnt = scnt[t]; if (cnt > SCAP) cnt = SCAP;
            cnts[(size_t)fbid * NB + t] = cnt;              // block-major, coalesced
        }
        return;
    }

    // ---- gemm: 64 rows/block, 4 waves, wave w -> rows 16w..16w+15 ----
    int row0 = (gidx - gidx / 3 - 1) * 64;
    int lane = t & 63, w = t >> 6;
    int m = lane & 15, q = lane >> 4;

    int row = row0 + 16 * w + m;
    int rc = row < N_NODES ? row : N_NODES - 1;
    const float4* xr = (const float4*)(x + (size_t)rc * CH);
    bf16x8 afr[4];
    #pragma unroll
    for (int kk = 0; kk < 4; ++kk) {
        float4 a0 = xr[kk * 8 + q * 2];
        float4 a1 = xr[kk * 8 + q * 2 + 1];
        bf16x8 a;
        a[0] = (short)f2bf(a0.x); a[1] = (short)f2bf(a0.y);
        a[2] = (short)f2bf(a0.z); a[3] = (short)f2bf(a0.w);
        a[4] = (short)f2bf(a1.x); a[5] = (short)f2bf(a1.y);
        a[6] = (short)f2bf(a1.z); a[7] = (short)f2bf(a1.w);
        afr[kk] = a;
    }

    f32x4 acc[8];
    #pragma unroll
    for (int c = 0; c < 8; ++c) acc[c] = (f32x4){0.f, 0.f, 0.f, 0.f};

    // B fragments: inline f32->bf16 from global W (L2-hot; proven perf-neutral r0->r1)
    #pragma unroll
    for (int c = 0; c < 8; ++c) {
        int n = c * 16 + m;
        #pragma unroll
        for (int kk = 0; kk < 4; ++kk) {
            int k0 = kk * 32 + q * 8;
            bf16x8 b;
            #pragma unroll
            for (int j = 0; j < 8; ++j)
                b[j] = (short)f2bf(W[(size_t)(k0 + j) * CH + n]);
            acc[c] = __builtin_amdgcn_mfma_f32_16x16x32_bf16(afr[kk], b, acc[c], 0, 0, 0);
        }
    }

    #pragma unroll
    for (int c = 0; c < 8; ++c) {
        #pragma unroll
        for (int r = 0; r < 4; ++r) {
            int orow = row0 + 16 * w + q * 4 + r;
            if (orow < N_NODES)
                yh[(size_t)orow * CH + c * 16 + m] = (unsigned short)f2bf(acc[c][r]);
        }
    }
}

// ---- build: ONE 1024-thread block per bucket (16 waves = 4/SIMD TLP); bins all
// 256 rows at once (no slice filter -> every scanned edge lands; pedges read 1x,
// not 4x). Half-wave hw scans slices fb = hw, hw+32, ... 2-deep pipelined.
__global__ __launch_bounds__(1024) void k_build(const int* __restrict__ cnts,
                                                const unsigned* __restrict__ pedges,
                                                unsigned short* __restrict__ csrP,
                                                int* __restrict__ deg,
                                                float* __restrict__ dinv) {
    __shared__ unsigned short bins[256][SLOT];   // 32KB
    __shared__ int rcnt[256];
    int b = blockIdx.x;
    int t = threadIdx.x;
    if (t < 256) rcnt[t] = 0;
    __syncthreads();

    const unsigned NOEDGE = 0xffffffffu;         // col=0xffff impossible (col<50000... rlo=255,col=65535 never real)
    int hw = t >> 5, ln = t & 31;                // 32 half-waves
    int fb = hw;
    int cnt0 = (fb < FBLK) ? cnts[(size_t)fb * NB + b] : 0;
    unsigned u0 = (fb < FBLK && ln < cnt0) ? pedges[((size_t)b * FBLK + fb) * SCAP + ln] : NOEDGE;
    while (fb < FBLK) {
        int fb1 = fb + 32;
        int cnt1 = (fb1 < FBLK) ? cnts[(size_t)fb1 * NB + b] : 0;
        unsigned u1 = (fb1 < FBLK && ln < cnt1) ? pedges[((size_t)b * FBLK + fb1) * SCAP + ln] : NOEDGE;
        if (u0 != NOEDGE) {
            int rlo = u0 >> 16;
            int p = atomicAdd(&rcnt[rlo], 1);    // LDS atomic
            if (p < SLOT) bins[rlo][p] = (unsigned short)(u0 & 0xffff);
        }
        u0 = u1; fb = fb1;
    }
    __syncthreads();

    int row0 = b * 256;
    if (t < 256) {
        int row = row0 + t;
        if (row < N_NODES) {
            int d = rcnt[t];
            deg[row] = d;
            dinv[row] = rsqrtf((float)(d > 0 ? d : 1));
        }
    }
    int rmax = N_NODES - row0;
    if (rmax > 256) rmax = 256;
    uint4* dst = (uint4*)(csrP + (size_t)row0 * SLOT);
    const uint4* src = (const uint4*)bins;
    for (int k = t; k < rmax * 8; k += 1024)     // 8 uint4 per row (128B)
        dst[k] = src[k];
}

// ---- per-node gather-reduce: 16 y-row gathers in flight, dense dinv ----
__global__ __launch_bounds__(256) void k_agg(const int* __restrict__ deg,
                                             const float* __restrict__ dinv,
                                             const unsigned short* __restrict__ csrP,
                                             const unsigned short* __restrict__ yh,
                                             float* __restrict__ out) {
    int gid = blockIdx.x * 256 + threadIdx.x;
    int n = gid >> 6;
    int lane = threadIdx.x & 63;
    if (n >= N_NODES) return;
    int d = deg[n];
    int cnt = d < SLOT ? d : SLOT;
    float dr = dinv[n];
    const unsigned* __restrict__ y2 = (const unsigned*)yh;    // 2 bf16 per uint
    const uint4* __restrict__ crow = (const uint4*)(csrP + (size_t)n * SLOT);
    float ax = 0.f, ay = 0.f;
    int j = 0;
    for (; j + 16 <= cnt; j += 16) {          // 16 independent gathers in flight
        uint4 ca = crow[j >> 3];
        uint4 cb = crow[(j >> 3) + 1];
        int c_[16];
        c_[0] = ca.x & 0xffff;  c_[1] = ca.x >> 16;
        c_[2] = ca.y & 0xffff;  c_[3] = ca.y >> 16;
        c_[4] = ca.z & 0xffff;  c_[5] = ca.z >> 16;
        c_[6] = ca.w & 0xffff;  c_[7] = ca.w >> 16;
        c_[8] = cb.x & 0xffff;  c_[9] = cb.x >> 16;
        c_[10] = cb.y & 0xffff; c_[11] = cb.y >> 16;
        c_[12] = cb.z & 0xffff; c_[13] = cb.z >> 16;
        c_[14] = cb.w & 0xffff; c_[15] = cb.w >> 16;
        unsigned v_[16];
        #pragma unroll
        for (int u = 0; u < 16; ++u) v_[u] = y2[c_[u] * 64 + lane];   // long-latency first
        float w_[16];
        #pragma unroll
        for (int u = 0; u < 16; ++u) w_[u] = dinv[c_[u]];             // L2-hot broadcast
        #pragma unroll
        for (int u = 0; u < 16; ++u) {
            ax = fmaf(bflo(v_[u]), w_[u], ax);
            ay = fmaf(bfhi(v_[u]), w_[u], ay);
        }
    }
    for (; j + 8 <= cnt; j += 8) {            // 8-wide mid loop
        uint4 cc = crow[j >> 3];
        int c0 = cc.x & 0xffff, c1 = cc.x >> 16;
        int c2 = cc.y & 0xffff, c3 = cc.y >> 16;
        int c4 = cc.z & 0xffff, c5 = cc.z >> 16;
        int c6 = cc.w & 0xffff, c7 = cc.w >> 16;
        unsigned v0 = y2[c0 * 64 + lane];
        unsigned v1 = y2[c1 * 64 + lane];
        unsigned v2 = y2[c2 * 64 + lane];
        unsigned v3 = y2[c3 * 64 + lane];
        unsigned v4 = y2[c4 * 64 + lane];
        unsigned v5 = y2[c5 * 64 + lane];
        unsigned v6 = y2[c6 * 64 + lane];
        unsigned v7 = y2[c7 * 64 + lane];
        float w0 = dinv[c0], w1 = dinv[c1], w2 = dinv[c2], w3 = dinv[c3];
        float w4 = dinv[c4], w5 = dinv[c5], w6 = dinv[c6], w7 = dinv[c7];
        ax = fmaf(bflo(v0), w0, ax); ay = fmaf(bfhi(v0), w0, ay);
        ax = fmaf(bflo(v1), w1, ax); ay = fmaf(bfhi(v1), w1, ay);
        ax = fmaf(bflo(v2), w2, ax); ay = fmaf(bfhi(v2), w2, ay);
        ax = fmaf(bflo(v3), w3, ax); ay = fmaf(bfhi(v3), w3, ay);
        ax = fmaf(bflo(v4), w4, ax); ay = fmaf(bfhi(v4), w4, ay);
        ax = fmaf(bflo(v5), w5, ax); ay = fmaf(bfhi(v5), w5, ay);
        ax = fmaf(bflo(v6), w6, ax); ay = fmaf(bfhi(v6), w6, ay);
        ax = fmaf(bflo(v7), w7, ax); ay = fmaf(bfhi(v7), w7, ay);
    }
    for (; j < cnt; ++j) {
        int c = csrP[(size_t)n * SLOT + j];
        float wc = dinv[c];
        unsigned v = y2[c * 64 + lane];
        ax = fmaf(bflo(v), wc, ax); ay = fmaf(bfhi(v), wc, ay);
    }
    ((float2*)out)[n * 64 + lane] = make_float2(ax * dr, ay * dr);
}

extern "C" void kernel_launch(void* const* d_in, const int* in_sizes, int n_in,
                              void* d_out, int out_size, void* d_ws, size_t ws_size,
                              hipStream_t stream) {
    const float* x = (const float*)d_in[0];
    const float* W = (const float*)d_in[1];
    const int* edge = (const int*)d_in[2];
    const int* rowv = edge;            // edge_index[0][:]
    const int* colv = edge + N_EDGES;  // edge_index[1][:]
    float* out = (float*)d_out;

    // ws layout: pedges(u32 private slices) | cnts | csrP(u16) | yh(bf16) | deg | dinv (~30MB)
    char* p = (char*)d_ws;
    unsigned* pedges = (unsigned*)p;               p += (size_t)NB * FBLK * SCAP * 4;   // 9.8 MB
    int* cnts = (int*)p;                           p += (size_t)FBLK * NB * 4;          // 307 KB
    unsigned short* csrP = (unsigned short*)p;     p += (size_t)N_NODES * SLOT * 2;     // 6.4 MB
    unsigned short* yh = (unsigned short*)p;       p += (size_t)N_NODES * CH * 2;       // 12.8 MB
    int* deg = (int*)p;                            p += (size_t)N_NODES * 4;
    float* dinv = (float*)p;                       // + N_NODES*4

    k_fgA  <<<GRID, 256, 0, stream>>>(rowv, colv, x, W, pedges, cnts, yh);
    k_build<<<NB, 1024, 0, stream>>>(cnts, pedges, csrP, deg, dinv);
    k_agg  <<<(N_NODES * 64 + 255) / 256, 256, 0, stream>>>(deg, dinv, csrP, yh, out);
}